// Round 21
// baseline (96.272 us; speedup 1.0000x reference)
//
#include <hip/hip_runtime.h>

typedef __bf16 bf16x8 __attribute__((ext_vector_type(8)));
typedef float f32x4 __attribute__((ext_vector_type(4)));
typedef float f32x16 __attribute__((ext_vector_type(16)));
typedef unsigned short u16x8 __attribute__((ext_vector_type(8)));
typedef unsigned short u16x4 __attribute__((ext_vector_type(4)));
typedef unsigned int u32x4 __attribute__((ext_vector_type(4)));
typedef int i32x2 __attribute__((ext_vector_type(2)));

__device__ inline unsigned short f2bf(float f) {
    __bf16 h = (__bf16)f;
    return __builtin_bit_cast(unsigned short, h);
}

__device__ inline float bf2f(unsigned short u) {
    unsigned int x = ((unsigned int)u) << 16;
    return __builtin_bit_cast(float, x);
}

__device__ inline unsigned int pkbf(float lo, float hi) {
    return (unsigned int)f2bf(lo) | ((unsigned int)f2bf(hi) << 16);
}

__device__ inline float fexp2(float x) {
#if __has_builtin(__builtin_amdgcn_exp2f)
    return __builtin_amdgcn_exp2f(x);
#else
    return exp2f(x);
#endif
}

__device__ inline f32x4 mfma16(u16x8 a, u16x8 b, f32x4 c) {
    return __builtin_amdgcn_mfma_f32_16x16x32_bf16(
        __builtin_bit_cast(bf16x8, a), __builtin_bit_cast(bf16x8, b), c, 0, 0, 0);
}

__device__ inline f32x16 mfma32(u16x8 a, u16x8 b, f32x16 c) {
    return __builtin_amdgcn_mfma_f32_32x32x16_bf16(
        __builtin_bit_cast(bf16x8, a), __builtin_bit_cast(bf16x8, b), c, 0, 0, 0);
}

__device__ inline i32x2 permswap(unsigned int a, unsigned int b, int hi) {
#if __has_builtin(__builtin_amdgcn_permlane32_swap)
    (void)hi;
    return __builtin_amdgcn_permlane32_swap((int)a, (int)b, false, false);
#else
    int pa_ = __shfl_xor((int)a, 32);
    int pb_ = __shfl_xor((int)b, 32);
    i32x2 r;
    r[0] = hi ? pb_ : (int)a;
    r[1] = hi ? (int)b : pa_;
    return r;
#endif
}

__device__ inline void gld_lds16(const unsigned short* gsrc, unsigned short* ldst) {
    __builtin_amdgcn_global_load_lds(
        (const __attribute__((address_space(1))) unsigned int*)gsrc,
        (__attribute__((address_space(3))) unsigned int*)ldst, 16, 0, 0);
}

#define WAIT_VM(n)                                          \
    asm volatile("s_waitcnt vmcnt(" #n ")" ::: "memory");   \
    __builtin_amdgcn_sched_barrier(0)
#define WAIT_LGKM0                                          \
    asm volatile("s_waitcnt lgkmcnt(0)" ::: "memory");      \
    __builtin_amdgcn_sched_barrier(0)
#define BARRIER                                             \
    __builtin_amdgcn_s_barrier();                           \
    __builtin_amdgcn_sched_barrier(0)

// ---------------- elementwise f32 -> bf16 ----------------
__global__ __launch_bounds__(256) void cvt_f32_bf16(const float* __restrict__ in,
                                                    unsigned short* __restrict__ out, long n) {
    long i = ((long)blockIdx.x * blockDim.x + threadIdx.x) * 4;
    if (i >= n) return;
    float4 v = *(const float4*)(in + i);
    ushort4 r;
    r.x = f2bf(v.x); r.y = f2bf(v.y); r.z = f2bf(v.z); r.w = f2bf(v.w);
    *(ushort4*)(out + i) = r;
}

// ---------------- all weight transposes in one launch (z selects target) ----------------
__global__ __launch_bounds__(256) void prep_weights(const float* __restrict__ Wq,
                                                    const float* __restrict__ Wkv,
                                                    const float* __restrict__ Wo,
                                                    unsigned short* __restrict__ WqkvT,
                                                    unsigned short* __restrict__ WoT,
                                                    float qscale) {
    __shared__ float tile[64][65];
    const int z = blockIdx.z;
    if (z != 1 && blockIdx.x >= 8) return;
    const float* W = (z == 0) ? Wq : (z == 1) ? Wkv : Wo;
    unsigned short* Wt = (z == 0) ? WqkvT : (z == 1) ? (WqkvT + 512L * 512) : WoT;
    const int N = (z == 1) ? 1024 : 512;
    const float scale = (z == 0) ? qscale : 1.0f;
    const int K = 512;
    const int n0 = blockIdx.x * 64, k0 = blockIdx.y * 64;
    const int c = threadIdx.x & 63;
    const int r4 = threadIdx.x >> 6;
#pragma unroll
    for (int i = 0; i < 16; i++) {
        int r = r4 * 16 + i;
        tile[r][c] = W[(long)(k0 + r) * N + n0 + c];
    }
    __syncthreads();
#pragma unroll
    for (int i = 0; i < 16; i++) {
        int rr = r4 * 16 + i;
        Wt[(long)(n0 + rr) * K + k0 + c] = f2bf(tile[c][rr] * scale);
    }
}

// ---------------- per-batch mask prefix-scan: idx[b][j] = j-th unmasked row ----------------
__global__ __launch_bounds__(256) void scan_mask(const int* __restrict__ mask,
                                                 int* __restrict__ idx, int* __restrict__ cnt) {
    const int b = blockIdx.x;
    const int tid = threadIdx.x;
    __shared__ int wsum[4];
    int m[8]; int pc = 0;
#pragma unroll
    for (int k = 0; k < 8; k++) { m[k] = mask[b * 2048 + tid * 8 + k]; pc += (m[k] != 0); }
    int s = pc;
    const int lane = tid & 63;
    for (int off = 1; off < 64; off <<= 1) {
        int v = __shfl_up(s, off);
        if (lane >= off) s += v;
    }
    if (lane == 63) wsum[tid >> 6] = s;
    __syncthreads();
    int wbase = 0;
    for (int w = 0; w < (tid >> 6); w++) wbase += wsum[w];
    int run = wbase + s - pc;   // exclusive prefix
#pragma unroll
    for (int k = 0; k < 8; k++) if (m[k]) idx[b * 2048 + (run++)] = tid * 8 + k;
    if (tid == 255) cnt[b] = wbase + s;
}

// ---------------- fused qkv GEMM: C = x @ [Wq|Wk|Wv]; V panel written TRANSPOSED ----------------
__global__ __launch_bounds__(256) void gemm_qkv(const unsigned short* __restrict__ A,
                                                const unsigned short* __restrict__ Bt,
                                                unsigned short* __restrict__ qkb,
                                                unsigned short* __restrict__ vT) {
    const int K = 512;
    __shared__ unsigned short AsL[2][128 * 32];
    __shared__ unsigned short BsL[2][128 * 32];
    const int tid = threadIdx.x;
    const int lane = tid & 63;
    const int wid = tid >> 6;
    const int lg = lane >> 4, lr = lane & 15;
    const int wm = wid >> 1, wn = wid & 1;
    const long m0 = (long)blockIdx.y * 128, n0 = (long)blockIdx.x * 128;

    f32x4 acc[4][4] = {};

    const unsigned short* aS0 = A  + (m0 + (tid >> 2)) * K + (tid & 3) * 8;
    const unsigned short* aS1 = A  + (m0 + 64 + (tid >> 2)) * K + (tid & 3) * 8;
    const unsigned short* bS0 = Bt + (n0 + (tid >> 2)) * K + (tid & 3) * 8;
    const unsigned short* bS1 = Bt + (n0 + 64 + (tid >> 2)) * K + (tid & 3) * 8;

#define GSTAGE(bufi, k0v)                                    \
    {                                                        \
        gld_lds16(aS0 + (k0v), &AsL[bufi][wid * 512]);       \
        gld_lds16(aS1 + (k0v), &AsL[bufi][2048 + wid * 512]);\
        gld_lds16(bS0 + (k0v), &BsL[bufi][wid * 512]);       \
        gld_lds16(bS1 + (k0v), &BsL[bufi][2048 + wid * 512]);\
    }
#define GREAD(cur)                                                                    \
    {                                                                                 \
        _Pragma("unroll")                                                             \
        for (int i = 0; i < 4; i++) {                                                 \
            af[i]  = *(const u16x8*)&AsL[cur][(wm * 64 + i * 16 + lr) * 32 + lg * 8]; \
            bfr[i] = *(const u16x8*)&BsL[cur][(wn * 64 + i * 16 + lr) * 32 + lg * 8]; \
        }                                                                             \
    }
#define GMFMA                                                                  \
    {                                                                          \
        _Pragma("unroll")                                                      \
        for (int i = 0; i < 4; i++)                                            \
            _Pragma("unroll")                                                  \
            for (int j = 0; j < 4; j++)                                        \
                acc[i][j] = mfma16(af[i], bfr[j], acc[i][j]);                  \
    }

    const int nk = K >> 5;
    GSTAGE(0, 0);
    GSTAGE(1, 32);
    for (int t = 0; t < nk - 1; t++) {
        const int cur = t & 1;
        u16x8 af[4], bfr[4];
        WAIT_VM(4);
        BARRIER;
        GREAD(cur);
        WAIT_LGKM0;
        BARRIER;
        if (t < nk - 2) GSTAGE(cur, (t + 2) * 32);
        GMFMA;
    }
    {
        u16x8 af[4], bfr[4];
        WAIT_VM(0);
        BARRIER;
        GREAD((nk - 1) & 1);
        GMFMA;
    }
#undef GSTAGE
#undef GREAD
#undef GMFMA

    if (n0 < 1024) {
#pragma unroll
        for (int i = 0; i < 4; i++)
#pragma unroll
            for (int j = 0; j < 4; j++)
#pragma unroll
                for (int r = 0; r < 4; r++) {
                    long row = m0 + wm * 64 + i * 16 + lg * 4 + r;
                    long col = n0 + wn * 64 + j * 16 + lr;
                    qkb[row * 1024 + col] = f2bf(acc[i][j][r]);
                }
    } else {
#pragma unroll
        for (int i = 0; i < 4; i++)
#pragma unroll
            for (int j = 0; j < 4; j++) {
                long vd = n0 - 1024 + wn * 64 + j * 16 + lr;
                long tok0 = m0 + wm * 64 + i * 16 + lg * 4;
                u16x4 st;
#pragma unroll
                for (int r = 0; r < 4; r++) st[r] = f2bf(acc[i][j][r]);
                *(u16x4*)&vT[vd * 8192 + tok0] = st;
            }
    }
}

// ---------------- GEMM: C[m][n] = sum_k A[m][k] * Bt[n][k] (masked f32 out) ----------------
template<int WRITE_BF16, int MASKED>
__global__ __launch_bounds__(256) void gemm_bt(const unsigned short* __restrict__ A,
                                               const unsigned short* __restrict__ Bt,
                                               void* __restrict__ Cv,
                                               int M, int N, int K,
                                               const int* __restrict__ mask) {
    __shared__ unsigned short AsL[2][128 * 32];
    __shared__ unsigned short BsL[2][128 * 32];
    const int tid = threadIdx.x;
    const int lane = tid & 63;
    const int wid = tid >> 6;
    const int lg = lane >> 4, lr = lane & 15;
    const int wm = wid >> 1, wn = wid & 1;
    const long m0 = (long)blockIdx.y * 128, n0 = (long)blockIdx.x * 128;

    f32x4 acc[4][4] = {};

    const unsigned short* aS0 = A  + (m0 + (tid >> 2)) * K + (tid & 3) * 8;
    const unsigned short* aS1 = A  + (m0 + 64 + (tid >> 2)) * K + (tid & 3) * 8;
    const unsigned short* bS0 = Bt + (n0 + (tid >> 2)) * K + (tid & 3) * 8;
    const unsigned short* bS1 = Bt + (n0 + 64 + (tid >> 2)) * K + (tid & 3) * 8;

#define GSTAGE(bufi, k0v)                                    \
    {                                                        \
        gld_lds16(aS0 + (k0v), &AsL[bufi][wid * 512]);       \
        gld_lds16(aS1 + (k0v), &AsL[bufi][2048 + wid * 512]);\
        gld_lds16(bS0 + (k0v), &BsL[bufi][wid * 512]);       \
        gld_lds16(bS1 + (k0v), &BsL[bufi][2048 + wid * 512]);\
    }
#define GREAD(cur)                                                                    \
    {                                                                                 \
        _Pragma("unroll")                                                             \
        for (int i = 0; i < 4; i++) {                                                 \
            af[i]  = *(const u16x8*)&AsL[cur][(wm * 64 + i * 16 + lr) * 32 + lg * 8]; \
            bfr[i] = *(const u16x8*)&BsL[cur][(wn * 64 + i * 16 + lr) * 32 + lg * 8]; \
        }                                                                             \
    }
#define GMFMA                                                                  \
    {                                                                          \
        _Pragma("unroll")                                                      \
        for (int i = 0; i < 4; i++)                                            \
            _Pragma("unroll")                                                  \
            for (int j = 0; j < 4; j++)                                        \
                acc[i][j] = mfma16(af[i], bfr[j], acc[i][j]);                  \
    }

    const int nk = K >> 5;
    GSTAGE(0, 0);
    GSTAGE(1, 32);
    for (int t = 0; t < nk - 1; t++) {
        const int cur = t & 1;
        u16x8 af[4], bfr[4];
        WAIT_VM(4);
        BARRIER;
        GREAD(cur);
        WAIT_LGKM0;
        BARRIER;
        if (t < nk - 2) GSTAGE(cur, (t + 2) * 32);
        GMFMA;
    }
    {
        u16x8 af[4], bfr[4];
        WAIT_VM(0);
        BARRIER;
        GREAD((nk - 1) & 1);
        GMFMA;
    }
#undef GSTAGE
#undef GREAD
#undef GMFMA

#pragma unroll
    for (int i = 0; i < 4; i++)
#pragma unroll
        for (int j = 0; j < 4; j++)
#pragma unroll
            for (int r = 0; r < 4; r++) {
                long row = m0 + wm * 64 + i * 16 + lg * 4 + r;
                long col = n0 + wn * 64 + j * 16 + lr;
                float v = acc[i][j][r];
                if (MASKED) {
                    if (!mask[row]) v = 0.0f;
                    ((float*)Cv)[row * N + col] = v;
                } else if (WRITE_BF16) {
                    ((unsigned short*)Cv)[row * N + col] = f2bf(v);
                } else {
                    ((float*)Cv)[row * N + col] = v;
                }
            }
}

// ---------------- flash attention: cross-block KV split (ks), 32KB LDS, 4 waves/SIMD ----------------
// grid 2048 worst-case (XCD-group swizzled), 256 threads = 4 waves (qh x kvh).
// Block owns 64 compacted q x KV-half ks (1024 kv). Wave (qh,kvh): 32 q x kv-quarter
// (512 kv = 16 tiles of KVBLK=32, qh-pair shares tile, each stages 2K+2V loads).
// LDS 32 KB -> 4-5 blocks/CU resident; ~1024 active blocks -> 4 waves/SIMD.
// Output: UNNORMALIZED partial O (bf16, pO[ks]) + l (f32, pL) — combined by combine_ks.
__global__ __launch_bounds__(256) void attn_kernel(const unsigned short* __restrict__ qk,
                                                   const unsigned short* __restrict__ vT,
                                                   unsigned short* __restrict__ pO0,
                                                   unsigned short* __restrict__ pO1,
                                                   float* __restrict__ pL,
                                                   const int* __restrict__ idxm,
                                                   const int* __restrict__ cntm) {
    const int Nseq = 2048, LD = 1024;
    const long T = 8192;
    const int id = blockIdx.x;
    const int xcd = id & 7, jj = id >> 3;      // jj 0..255
    const int g = xcd + 8 * (jj & 3);          // group = h + 8*b, 4 groups per XCD
    const int rem = jj >> 2;                   // 0..63
    const int qt = rem >> 1;                   // 0..31 (64-q tiles)
    const int ks = rem & 1;                    // KV half
    const int b = g >> 3, h = g & 7;

    const int count = cntm[b];
    if (qt * 64 >= count) return;              // block-uniform early exit

    const int tid = threadIdx.x;
    const int wid = tid >> 6, lane = tid & 63;
    const int qL = lane & 31, hi = lane >> 5;
    const int qh = wid >> 1, kvh = wid & 1;

    __shared__ unsigned short LDSB[2][2][4096];   // [kvh][buf][K 2048 | V 2048] shorts

    // ---- gathered Q fragments ----
    const int i_q = qt * 64 + qh * 32 + qL;
    const int gi = idxm[b * 2048 + (i_q < count ? i_q : count - 1)];
    const long qrow = (long)b * Nseq + gi;
    u16x8 qf[4];
#pragma unroll
    for (int j = 0; j < 4; j++)
        qf[j] = *(const u16x8*)(qk + qrow * LD + h * 64 + 16 * j + 8 * hi);

    f32x16 oacc[2] = {};     // [db]: partial O[q=crow(reg,hi)][d=db*32+qL]
    f32x16 lacc = {};        // partial l[q=crow(reg,hi)]
    u16x8 onesf;
#pragma unroll
    for (int e = 0; e < 8; e++) onesf[e] = 0x3F80;  // bf16 1.0

    // ---- staging sources: kv origin = ks*1024 + kvh*512; wave stages qh-half of tile ----
    // K tile [32 kv][64 d]: row R = qh*16 + i*8 + Rs; content granule p0 ^ Rs
    const int Rs = lane >> 3, p0 = lane & 7;
    const unsigned short* kS = qk + 512
        + ((long)b * Nseq + ks * 1024 + kvh * 512 + qh * 16 + Rs) * LD + h * 64
        + ((p0 ^ Rs) * 8);
    // V tile [64 d][32 kv]: d-row r = qh*32 + i*16 + rV; content granule pV ^ ((rV>>1)&3)
    const int rV = lane >> 2, pV = lane & 3;
    const unsigned short* vS = vT + ((long)h * 64 + qh * 32 + rV) * T
        + (long)b * Nseq + ks * 1024 + kvh * 512 + ((pV ^ ((lane >> 3) & 3)) * 8);
    const int rsw = qL & 7;

#define STAGE(bufi)                                                              \
    {                                                                            \
        unsigned short* dK = &LDSB[kvh][bufi][0];                                \
        _Pragma("unroll")                                                        \
        for (int i = 0; i < 2; i++)                                              \
            gld_lds16(kS + (long)i * 8 * LD, dK + qh * 1024 + i * 512);          \
        _Pragma("unroll")                                                        \
        for (int i = 0; i < 2; i++)                                              \
            gld_lds16(vS + (long)i * 16 * T, dK + 2048 + qh * 1024 + i * 512);   \
        kS += 32L * LD; vS += 32;                                                \
    }

#define READ_KF(buf)                                                             \
    {                                                                            \
        _Pragma("unroll")                                                        \
        for (int j = 0; j < 4; j++)                                              \
            kf[j] = *(const u16x8*)&LDSB[kvh][buf][qL * 64                       \
                                        + (((2 * j + hi) ^ rsw) * 8)];           \
    }
#define READ_VF(buf)                                                             \
    {                                                                            \
        _Pragma("unroll")                                                        \
        for (int db = 0; db < 2; db++)                                           \
            _Pragma("unroll")                                                    \
            for (int jk = 0; jk < 2; jk++)                                       \
                vf[db][jk] = *(const u16x8*)&LDSB[kvh][buf][2048                 \
                                 + (db * 32 + qL) * 32                           \
                                 + (((2 * jk + hi) ^ ((qL >> 1) & 3)) * 8)];     \
    }

#define QKNEXT(SN)                                                               \
    {                                                                            \
        SN = (f32x16){};                                                         \
        _Pragma("unroll")                                                        \
        for (int j = 0; j < 4; j++) SN = mfma32(kf[j], qf[j], SN);               \
    }

#define PACK_PV(SC)                                                                    \
    {                                                                                  \
        unsigned int w[8];                                                             \
        _Pragma("unroll")                                                              \
        for (int i = 0; i < 8; i++)                                                    \
            w[i] = pkbf(fexp2(SC[2 * i]), fexp2(SC[2 * i + 1]));                       \
        u16x8 pa[2];                                                                   \
        _Pragma("unroll")                                                              \
        for (int hh = 0; hh < 2; hh++) {                                               \
            i32x2 ra = permswap(w[4 * hh + 0], w[4 * hh + 2], hi);                     \
            i32x2 rb = permswap(w[4 * hh + 1], w[4 * hh + 3], hi);                     \
            u32x4 fw;                                                                  \
            fw[0] = (unsigned)ra[0]; fw[1] = (unsigned)rb[0];                          \
            fw[2] = (unsigned)ra[1]; fw[3] = (unsigned)rb[1];                          \
            pa[hh] = __builtin_bit_cast(u16x8, fw);                                    \
        }                                                                              \
        _Pragma("unroll")                                                              \
        for (int jk = 0; jk < 2; jk++) {                                               \
            lacc = mfma32(pa[jk], onesf, lacc);                                        \
            oacc[0] = mfma32(pa[jk], vf[0][jk], oacc[0]);                              \
            oacc[1] = mfma32(pa[jk], vf[1][jk], oacc[1]);                              \
        }                                                                              \
    }

// consume tile t (buf cur): drain through K(t+1) -> vmcnt(2) leaves V(t+1) in flight
#define STEP(SC, SN, cur)                                                        \
    {                                                                            \
        WAIT_VM(2);                                                              \
        BARRIER;                                                                 \
        READ_VF(cur);                                                            \
        READ_KF(cur ^ 1);                                                        \
        WAIT_LGKM0;                                                              \
        BARRIER;                                                                 \
        STAGE(cur);                                                              \
        QKNEXT(SN);                                                              \
        PACK_PV(SC);                                                             \
    }

    u16x8 kf[4], vf[2][2];
    f32x16 sA, sB;

    // ---- prologue: queue [K0(2) V0(2) K1(2) V1(2)]; drain K0 -> vmcnt(6) ----
    STAGE(0);
    STAGE(1);
    WAIT_VM(6);
    BARRIER;
    READ_KF(0);
    WAIT_LGKM0;
    QKNEXT(sA);

    // ---- main loop: 16 tiles ----
    for (int t = 0; t < 14; t += 2) {
        STEP(sA, sB, 0);   // consume even tile t
        STEP(sB, sA, 1);   // consume odd tile t+1
    }
    {   // t = 14: no stage
        WAIT_VM(2);
        BARRIER;
        READ_VF(0);
        READ_KF(1);
        WAIT_LGKM0;
        QKNEXT(sB);
        PACK_PV(sA);
    }
    {   // t = 15: PV only
        WAIT_VM(0);
        BARRIER;
        READ_VF(1);
        WAIT_LGKM0;
        PACK_PV(sB);
    }
#undef STAGE
#undef READ_KF
#undef READ_VF
#undef QKNEXT
#undef PACK_PV
#undef STEP

    // ---- combine kvh pair, write UNNORMALIZED partial to pO[ks] + pL ----
    __syncthreads();
    float* Ox = (float*)&LDSB[0][0][0];   // [qh][32 crow][65 padded] = 16.6 KB
    float* lX = Ox + 2 * 2080;            // [qh][32 crow]

    if (kvh == 1) {
#pragma unroll
        for (int reg = 0; reg < 16; reg++) {
            const int crow = (reg & 3) + 8 * (reg >> 2) + 4 * hi;
            Ox[qh * 2080 + crow * 65 + qL]      = oacc[0][reg];
            Ox[qh * 2080 + crow * 65 + 32 + qL] = oacc[1][reg];
            lX[qh * 32 + crow] = lacc[reg];
        }
    }
    __syncthreads();
    if (kvh == 0) {
        unsigned short* pOks = ks ? pO1 : pO0;
#pragma unroll
        for (int reg = 0; reg < 16; reg++) {
            const int crow = (reg & 3) + 8 * (reg >> 2) + 4 * hi;
            const int row_c = qt * 64 + qh * 32 + crow;
            if (row_c < count) {
                float lt = lacc[reg] + lX[qh * 32 + crow];
                float o0 = oacc[0][reg] + Ox[qh * 2080 + crow * 65 + qL];
                float o1 = oacc[1][reg] + Ox[qh * 2080 + crow * 65 + 32 + qL];
                long rowc = (long)b * 2048 + row_c;
                pOks[rowc * 512 + h * 64 + qL]      = f2bf(o0);
                pOks[rowc * 512 + h * 64 + 32 + qL] = f2bf(o1);
                pL[((ks * 4 + b) * 8 + h) * 2048 + row_c] = lt;  // lanes same value
            }
        }
    }
}

// ---------------- combine KV halves: res[orig] = (O0+O1)/(l0+l1), bf16 ----------------
// grid 2048 (= 4 b x 512), 256 thr = 4 waves; wave handles one compacted row.
__global__ __launch_bounds__(256) void combine_ks(const unsigned short* __restrict__ pO0,
                                                  const unsigned short* __restrict__ pO1,
                                                  const float* __restrict__ pL,
                                                  unsigned short* __restrict__ resOut,
                                                  const int* __restrict__ idxm,
                                                  const int* __restrict__ cntm) {
    const int b = blockIdx.x >> 9;
    const int r0 = (blockIdx.x & 511) * 4 + (threadIdx.x >> 6);
    if (r0 >= cntm[b]) return;   // wave-uniform
    const int lane = threadIdx.x & 63;
    const int h = lane >> 3;
    const long rowc = (long)b * 2048 + r0;
    u16x8 a = *(const u16x8*)&pO0[rowc * 512 + lane * 8];
    u16x8 c = *(const u16x8*)&pO1[rowc * 512 + lane * 8];
    float l0 = pL[((0 * 4 + b) * 8 + h) * 2048 + r0];
    float l1 = pL[((1 * 4 + b) * 8 + h) * 2048 + r0];
    float inv = 1.0f / (l0 + l1);
    const int orig = idxm[b * 2048 + r0];
    u16x8 o;
#pragma unroll
    for (int e = 0; e < 8; e++)
        o[e] = f2bf((bf2f(a[e]) + bf2f(c[e])) * inv);
    *(u16x8*)&resOut[((long)b * 2048 + orig) * 512 + lane * 8] = o;
}

extern "C" void kernel_launch(void* const* d_in, const int* in_sizes, int n_in,
                              void* d_out, int out_size, void* d_ws, size_t ws_size,
                              hipStream_t stream) {
    const float* x   = (const float*)d_in[0];
    const int* mask  = (const int*)d_in[1];
    const float* Wq  = (const float*)d_in[2];
    const float* Wkv = (const float*)d_in[3];
    const float* Wo  = (const float*)d_in[4];
    float* out = (float*)d_out;

    const int D = 512;
    const long T = 8192;
    const float QSCALE = 0.125f * 1.4426950408889634f;  // d^-0.5 * log2(e)

    unsigned short* ws    = (unsigned short*)d_ws;
    unsigned short* xb    = ws;                          // T*512 (later: pO0)
    unsigned short* WqkvT = xb    + T * D;               // 1536*512
    unsigned short* WoT   = WqkvT + 1536L * 512;         // 512*512
    unsigned short* qkb   = WoT   + 512L * 512;          // T*1024 (later: res_final)
    unsigned short* vTb   = qkb   + T * 1024;            // 512*T
    unsigned short* resb  = vTb   + 512L * T;            // T*512 (pO1)
    int* idxb = (int*)(resb + T * 512);                  // 4*2048 ints
    int* cntb = idxb + 4 * 2048;                         // 4 ints
    float* pLb = (float*)(cntb + 4);                     // 2*4*8*2048 f32 = 512 KB

    cvt_f32_bf16<<<(int)(T * D / 1024), 256, 0, stream>>>(x, xb, T * D);
    prep_weights<<<dim3(16, 8, 3), 256, 0, stream>>>(Wq, Wkv, Wo, WqkvT, WoT, QSCALE);
    scan_mask<<<4, 256, 0, stream>>>(mask, idxb, cntb);

    // fused: qk (row-major) + vT (transposed write) = x @ [Wq*a|Wk|Wv]
    gemm_qkv<<<dim3(12, 64), 256, 0, stream>>>(xb, WqkvT, qkb, vTb);

    // attention: cross-block KV split; partials -> pO0(=xb, dead), pO1(=resb), pL
    attn_kernel<<<2048, 256, 0, stream>>>(qkb, vTb, xb, resb, pLb, idxb, cntb);

    // combine halves, normalize, scatter to original rows -> res_final in qkb (dead region)
    unsigned short* resF = qkb;
    combine_ks<<<2048, 256, 0, stream>>>(xb, resb, pLb, resF, idxb, cntb);

    // out = mask ? res @ Wo : 0   (masked rows hold stale data; output forced to 0)
    gemm_bt<0, 1><<<dim3(4, 64), 256, 0, stream>>>(resF, WoT, out, T, D, D, mask);
}

// Round 22
// 91.045 us; speedup vs baseline: 1.0574x; 1.0574x over previous
//
#include <hip/hip_runtime.h>

typedef __bf16 bf16x8 __attribute__((ext_vector_type(8)));
typedef float f32x4 __attribute__((ext_vector_type(4)));
typedef float f32x16 __attribute__((ext_vector_type(16)));
typedef unsigned short u16x8 __attribute__((ext_vector_type(8)));
typedef unsigned short u16x4 __attribute__((ext_vector_type(4)));
typedef unsigned int u32x4 __attribute__((ext_vector_type(4)));
typedef int i32x2 __attribute__((ext_vector_type(2)));

__device__ inline unsigned short f2bf(float f) {
    __bf16 h = (__bf16)f;
    return __builtin_bit_cast(unsigned short, h);
}

__device__ inline unsigned int pkbf(float lo, float hi) {
    return (unsigned int)f2bf(lo) | ((unsigned int)f2bf(hi) << 16);
}

__device__ inline float fexp2(float x) {
#if __has_builtin(__builtin_amdgcn_exp2f)
    return __builtin_amdgcn_exp2f(x);
#else
    return exp2f(x);
#endif
}

__device__ inline f32x4 mfma16(u16x8 a, u16x8 b, f32x4 c) {
    return __builtin_amdgcn_mfma_f32_16x16x32_bf16(
        __builtin_bit_cast(bf16x8, a), __builtin_bit_cast(bf16x8, b), c, 0, 0, 0);
}

__device__ inline f32x16 mfma32(u16x8 a, u16x8 b, f32x16 c) {
    return __builtin_amdgcn_mfma_f32_32x32x16_bf16(
        __builtin_bit_cast(bf16x8, a), __builtin_bit_cast(bf16x8, b), c, 0, 0, 0);
}

__device__ inline i32x2 permswap(unsigned int a, unsigned int b, int hi) {
#if __has_builtin(__builtin_amdgcn_permlane32_swap)
    (void)hi;
    return __builtin_amdgcn_permlane32_swap((int)a, (int)b, false, false);
#else
    int pa_ = __shfl_xor((int)a, 32);
    int pb_ = __shfl_xor((int)b, 32);
    i32x2 r;
    r[0] = hi ? pb_ : (int)a;
    r[1] = hi ? (int)b : pa_;
    return r;
#endif
}

__device__ inline void gld_lds16(const unsigned short* gsrc, unsigned short* ldst) {
    __builtin_amdgcn_global_load_lds(
        (const __attribute__((address_space(1))) unsigned int*)gsrc,
        (__attribute__((address_space(3))) unsigned int*)ldst, 16, 0, 0);
}

#define WAIT_VM(n)                                          \
    asm volatile("s_waitcnt vmcnt(" #n ")" ::: "memory");   \
    __builtin_amdgcn_sched_barrier(0)
#define WAIT_LGKM0                                          \
    asm volatile("s_waitcnt lgkmcnt(0)" ::: "memory");      \
    __builtin_amdgcn_sched_barrier(0)
#define BARRIER                                             \
    __builtin_amdgcn_s_barrier();                           \
    __builtin_amdgcn_sched_barrier(0)

// ---------------- merged preamble: cvt (4096) | prep_weights (384) | scan_mask (4) ----------------
__global__ __launch_bounds__(256) void preamble(const float* __restrict__ x,
                                                unsigned short* __restrict__ xb,
                                                const float* __restrict__ Wq,
                                                const float* __restrict__ Wkv,
                                                const float* __restrict__ Wo,
                                                unsigned short* __restrict__ WqkvT,
                                                unsigned short* __restrict__ WoT,
                                                float qscale,
                                                const int* __restrict__ mask,
                                                int* __restrict__ idx,
                                                int* __restrict__ cnt) {
    __shared__ float tile[64][65];
    __shared__ int wsum[4];
    const int bid = blockIdx.x;
    const int tid = threadIdx.x;

    if (bid < 4096) {
        // x f32 -> bf16, 4 elems/thread
        long i = ((long)bid * 256 + tid) * 4;
        float4 v = *(const float4*)(x + i);
        ushort4 r;
        r.x = f2bf(v.x); r.y = f2bf(v.y); r.z = f2bf(v.z); r.w = f2bf(v.w);
        *(ushort4*)(xb + i) = r;
    } else if (bid < 4480) {
        // tiled weight transpose; flat = z*128 + by*16 + bx
        const int flat = bid - 4096;
        const int z = flat >> 7;
        const int by = (flat >> 4) & 7, bx = flat & 15;
        if (z != 1 && bx >= 8) return;
        const float* W = (z == 0) ? Wq : (z == 1) ? Wkv : Wo;
        unsigned short* Wt = (z == 0) ? WqkvT : (z == 1) ? (WqkvT + 512L * 512) : WoT;
        const int N = (z == 1) ? 1024 : 512;
        const float scale = (z == 0) ? qscale : 1.0f;
        const int n0 = bx * 64, k0 = by * 64;
        const int c = tid & 63;
        const int r4 = tid >> 6;
#pragma unroll
        for (int i = 0; i < 16; i++) {
            int r = r4 * 16 + i;
            tile[r][c] = W[(long)(k0 + r) * N + n0 + c];
        }
        __syncthreads();
#pragma unroll
        for (int i = 0; i < 16; i++) {
            int rr = r4 * 16 + i;
            Wt[(long)(n0 + rr) * 512 + k0 + c] = f2bf(tile[c][rr] * scale);
        }
    } else {
        // per-batch mask prefix-scan
        const int b = bid - 4480;
        int m[8]; int pc = 0;
#pragma unroll
        for (int k = 0; k < 8; k++) { m[k] = mask[b * 2048 + tid * 8 + k]; pc += (m[k] != 0); }
        int s = pc;
        const int lane = tid & 63;
        for (int off = 1; off < 64; off <<= 1) {
            int v = __shfl_up(s, off);
            if (lane >= off) s += v;
        }
        if (lane == 63) wsum[tid >> 6] = s;
        __syncthreads();
        int wbase = 0;
        for (int w = 0; w < (tid >> 6); w++) wbase += wsum[w];
        int run = wbase + s - pc;   // exclusive prefix
#pragma unroll
        for (int k = 0; k < 8; k++) if (m[k]) idx[b * 2048 + (run++)] = tid * 8 + k;
        if (tid == 255) cnt[b] = wbase + s;
    }
}

// ---------------- fused qkv GEMM: C = x @ [Wq|Wk|Wv]; V panel written TRANSPOSED ----------------
__global__ __launch_bounds__(256) void gemm_qkv(const unsigned short* __restrict__ A,
                                                const unsigned short* __restrict__ Bt,
                                                unsigned short* __restrict__ qkb,
                                                unsigned short* __restrict__ vT) {
    const int K = 512;
    __shared__ unsigned short AsL[2][128 * 32];
    __shared__ unsigned short BsL[2][128 * 32];
    const int tid = threadIdx.x;
    const int lane = tid & 63;
    const int wid = tid >> 6;
    const int lg = lane >> 4, lr = lane & 15;
    const int wm = wid >> 1, wn = wid & 1;
    const long m0 = (long)blockIdx.y * 128, n0 = (long)blockIdx.x * 128;

    f32x4 acc[4][4] = {};

    const unsigned short* aS0 = A  + (m0 + (tid >> 2)) * K + (tid & 3) * 8;
    const unsigned short* aS1 = A  + (m0 + 64 + (tid >> 2)) * K + (tid & 3) * 8;
    const unsigned short* bS0 = Bt + (n0 + (tid >> 2)) * K + (tid & 3) * 8;
    const unsigned short* bS1 = Bt + (n0 + 64 + (tid >> 2)) * K + (tid & 3) * 8;

#define GSTAGE(bufi, k0v)                                    \
    {                                                        \
        gld_lds16(aS0 + (k0v), &AsL[bufi][wid * 512]);       \
        gld_lds16(aS1 + (k0v), &AsL[bufi][2048 + wid * 512]);\
        gld_lds16(bS0 + (k0v), &BsL[bufi][wid * 512]);       \
        gld_lds16(bS1 + (k0v), &BsL[bufi][2048 + wid * 512]);\
    }
#define GREAD(cur)                                                                    \
    {                                                                                 \
        _Pragma("unroll")                                                             \
        for (int i = 0; i < 4; i++) {                                                 \
            af[i]  = *(const u16x8*)&AsL[cur][(wm * 64 + i * 16 + lr) * 32 + lg * 8]; \
            bfr[i] = *(const u16x8*)&BsL[cur][(wn * 64 + i * 16 + lr) * 32 + lg * 8]; \
        }                                                                             \
    }
#define GMFMA                                                                  \
    {                                                                          \
        _Pragma("unroll")                                                      \
        for (int i = 0; i < 4; i++)                                            \
            _Pragma("unroll")                                                  \
            for (int j = 0; j < 4; j++)                                        \
                acc[i][j] = mfma16(af[i], bfr[j], acc[i][j]);                  \
    }

    const int nk = K >> 5;
    GSTAGE(0, 0);
    GSTAGE(1, 32);
    for (int t = 0; t < nk - 1; t++) {
        const int cur = t & 1;
        u16x8 af[4], bfr[4];
        WAIT_VM(4);
        BARRIER;
        GREAD(cur);
        WAIT_LGKM0;
        BARRIER;
        if (t < nk - 2) GSTAGE(cur, (t + 2) * 32);
        GMFMA;
    }
    {
        u16x8 af[4], bfr[4];
        WAIT_VM(0);
        BARRIER;
        GREAD((nk - 1) & 1);
        GMFMA;
    }
#undef GSTAGE
#undef GREAD
#undef GMFMA

    if (n0 < 1024) {
#pragma unroll
        for (int i = 0; i < 4; i++)
#pragma unroll
            for (int j = 0; j < 4; j++)
#pragma unroll
                for (int r = 0; r < 4; r++) {
                    long row = m0 + wm * 64 + i * 16 + lg * 4 + r;
                    long col = n0 + wn * 64 + j * 16 + lr;
                    qkb[row * 1024 + col] = f2bf(acc[i][j][r]);
                }
    } else {
#pragma unroll
        for (int i = 0; i < 4; i++)
#pragma unroll
            for (int j = 0; j < 4; j++) {
                long vd = n0 - 1024 + wn * 64 + j * 16 + lr;
                long tok0 = m0 + wm * 64 + i * 16 + lg * 4;
                u16x4 st;
#pragma unroll
                for (int r = 0; r < 4; r++) st[r] = f2bf(acc[i][j][r]);
                *(u16x4*)&vT[vd * 8192 + tok0] = st;
            }
    }
}

// ---------------- out GEMM: 128x64 tiles (2 blocks/CU), masked f32 out ----------------
__global__ __launch_bounds__(256) void gemm_out(const unsigned short* __restrict__ A,
                                                const unsigned short* __restrict__ Bt,
                                                float* __restrict__ Cv,
                                                const int* __restrict__ mask) {
    const int K = 512, N = 512;
    __shared__ unsigned short AsL[2][128 * 32];
    __shared__ unsigned short BsL[2][64 * 32];
    const int tid = threadIdx.x;
    const int lane = tid & 63;
    const int wid = tid >> 6;
    const int lg = lane >> 4, lr = lane & 15;
    const int wm = wid >> 1, wn = wid & 1;
    const long m0 = (long)blockIdx.y * 128, n0 = (long)blockIdx.x * 64;

    f32x4 acc[4][2] = {};

    const unsigned short* aS0 = A  + (m0 + (tid >> 2)) * K + (tid & 3) * 8;
    const unsigned short* aS1 = A  + (m0 + 64 + (tid >> 2)) * K + (tid & 3) * 8;
    const unsigned short* bS0 = Bt + (n0 + (tid >> 2)) * K + (tid & 3) * 8;

#define GSTAGE(bufi, k0v)                                    \
    {                                                        \
        gld_lds16(aS0 + (k0v), &AsL[bufi][wid * 512]);       \
        gld_lds16(aS1 + (k0v), &AsL[bufi][2048 + wid * 512]);\
        gld_lds16(bS0 + (k0v), &BsL[bufi][wid * 512]);       \
    }
#define GREAD(cur)                                                                    \
    {                                                                                 \
        _Pragma("unroll")                                                             \
        for (int i = 0; i < 4; i++)                                                   \
            af[i]  = *(const u16x8*)&AsL[cur][(wm * 64 + i * 16 + lr) * 32 + lg * 8]; \
        _Pragma("unroll")                                                             \
        for (int j = 0; j < 2; j++)                                                   \
            bfr[j] = *(const u16x8*)&BsL[cur][(wn * 32 + j * 16 + lr) * 32 + lg * 8]; \
    }
#define GMFMA                                                                  \
    {                                                                          \
        _Pragma("unroll")                                                      \
        for (int i = 0; i < 4; i++)                                            \
            _Pragma("unroll")                                                  \
            for (int j = 0; j < 2; j++)                                        \
                acc[i][j] = mfma16(af[i], bfr[j], acc[i][j]);                  \
    }

    const int nk = K >> 5;   // 16
    GSTAGE(0, 0);
    GSTAGE(1, 32);
    for (int t = 0; t < nk - 1; t++) {
        const int cur = t & 1;
        u16x8 af[4], bfr[2];
        WAIT_VM(3);
        BARRIER;
        GREAD(cur);
        WAIT_LGKM0;
        BARRIER;
        if (t < nk - 2) GSTAGE(cur, (t + 2) * 32);
        GMFMA;
    }
    {
        u16x8 af[4], bfr[2];
        WAIT_VM(0);
        BARRIER;
        GREAD((nk - 1) & 1);
        GMFMA;
    }
#undef GSTAGE
#undef GREAD
#undef GMFMA

#pragma unroll
    for (int i = 0; i < 4; i++)
#pragma unroll
        for (int j = 0; j < 2; j++)
#pragma unroll
            for (int r = 0; r < 4; r++) {
                long row = m0 + wm * 64 + i * 16 + lg * 4 + r;
                long col = n0 + wn * 32 + j * 16 + lr;
                float v = acc[i][j][r];
                if (!mask[row]) v = 0.0f;   // overrides stale res rows
                Cv[row * N + col] = v;
            }
}

// ---------------- flash attention (R17/R20 verbatim — best known: 47.5 us) ----------------
// grid 1024 worst-case (XCD-group swizzled), 256 threads = 4 waves. Block owns 64 compacted q.
// Wave (qh, kvh): 32 q-rows x KV-half kvh. The two waves of a kvh-pair SHARE one
// double-buffered KVBLK=64 tile (each stages half: 4K+4V loads) -> 16 iterations/wave.
__global__ __launch_bounds__(256) void attn_kernel(const unsigned short* __restrict__ qk,
                                                   const unsigned short* __restrict__ vT,
                                                   unsigned short* __restrict__ res,
                                                   const int* __restrict__ idxm,
                                                   const int* __restrict__ cntm) {
    const int Nseq = 2048, LD = 1024;
    const long T = 8192;
    const int id = blockIdx.x;
    const int xcd = id & 7, jj = id >> 3;      // jj 0..127
    const int g = xcd + 8 * (jj & 3);          // group = h + 8*b, 4 groups per XCD
    const int qt = jj >> 2;                    // 0..31 (64-q tiles)
    const int b = g >> 3, h = g & 7;

    const int count = cntm[b];
    if (qt * 64 >= count) return;              // block-uniform early exit

    const int tid = threadIdx.x;
    const int wid = tid >> 6, lane = tid & 63;
    const int qL = lane & 31, hi = lane >> 5;
    const int qh = wid >> 1, kvh = wid & 1;

    __shared__ unsigned short LDSB[2][2][8192];   // [kvh pair][buf][K 4096 | V 4096] shorts

    // ---- gathered Q fragments ----
    const int i_q = qt * 64 + qh * 32 + qL;
    const int gi = idxm[b * 2048 + (i_q < count ? i_q : count - 1)];
    const long qrow = (long)b * Nseq + gi;
    u16x8 qf[4];
#pragma unroll
    for (int j = 0; j < 4; j++)
        qf[j] = *(const u16x8*)(qk + qrow * LD + h * 64 + 16 * j + 8 * hi);

    f32x16 oacc[2] = {};     // [db]: partial O[q=crow(reg,hi)][d=db*32+qL] over this kv half
    f32x16 lacc = {};        // partial l[q=crow(reg,hi)]
    u16x8 onesf;
#pragma unroll
    for (int e = 0; e < 8; e++) onesf[e] = 0x3F80;  // bf16 1.0

    // ---- staging sources: wave stages rows 32*qh..+31 of its pair's 64-row tiles ----
    const int Rs = lane >> 3, p0 = lane & 7;
    const int psw = (p0 ^ Rs) * 8;
    const unsigned short* kS = qk + 512 + ((long)b * Nseq + kvh * 1024 + 32 * qh + Rs) * LD
                               + h * 64 + psw;
    const unsigned short* vS = vT + ((long)h * 64 + 32 * qh + Rs) * T + (long)b * Nseq
                               + kvh * 1024 + psw;
    const int rsw = qL & 7;

#define STAGE(bufi)                                                             \
    {                                                                           \
        _Pragma("unroll")                                                       \
        for (int i = 0; i < 4; i++)                                             \
            gld_lds16(kS + (long)i * 8 * LD,                                    \
                      &LDSB[kvh][bufi][(qh * 4 + i) * 512]);                    \
        _Pragma("unroll")                                                       \
        for (int i = 0; i < 4; i++)                                             \
            gld_lds16(vS + (long)i * 8 * T,                                     \
                      &LDSB[kvh][bufi][4096 + (qh * 4 + i) * 512]);             \
        kS += 64L * LD; vS += 64;                                               \
    }

#define READ_KF(buf)                                                            \
    {                                                                           \
        _Pragma("unroll")                                                       \
        for (int kvb = 0; kvb < 2; kvb++)                                       \
            _Pragma("unroll")                                                   \
            for (int j = 0; j < 4; j++)                                         \
                kf[kvb][j] = *(const u16x8*)&LDSB[kvh][buf][(kvb * 32 + qL) * 64\
                                             + (((2 * j + hi) ^ rsw) * 8)];     \
    }
#define READ_VF(buf)                                                            \
    {                                                                           \
        _Pragma("unroll")                                                       \
        for (int db = 0; db < 2; db++)                                          \
            _Pragma("unroll")                                                   \
            for (int jk = 0; jk < 4; jk++)                                      \
                vf[db][jk] = *(const u16x8*)&LDSB[kvh][buf][4096                \
                                 + (db * 32 + qL) * 64                          \
                                 + (((2 * jk + hi) ^ rsw) * 8)];                \
    }

#define QKNEXT(SN)                                                              \
    {                                                                           \
        SN[0] = (f32x16){}; SN[1] = (f32x16){};                                 \
        _Pragma("unroll")                                                       \
        for (int j = 0; j < 4; j++) {                                           \
            SN[0] = mfma32(kf[0][j], qf[j], SN[0]);                             \
            SN[1] = mfma32(kf[1][j], qf[j], SN[1]);                             \
        }                                                                       \
    }

#define PACK_PV(SC)                                                                    \
    {                                                                                  \
        u16x8 pa[4];                                                                   \
        _Pragma("unroll")                                                              \
        for (int kvb = 0; kvb < 2; kvb++) {                                            \
            unsigned int w[8];                                                         \
            _Pragma("unroll")                                                          \
            for (int i = 0; i < 8; i++)                                                \
                w[i] = pkbf(fexp2(SC[kvb][2 * i]), fexp2(SC[kvb][2 * i + 1]));         \
            _Pragma("unroll")                                                          \
            for (int hh = 0; hh < 2; hh++) {                                           \
                i32x2 ra = permswap(w[4 * hh + 0], w[4 * hh + 2], hi);                 \
                i32x2 rb = permswap(w[4 * hh + 1], w[4 * hh + 3], hi);                 \
                u32x4 fw;                                                              \
                fw[0] = (unsigned)ra[0]; fw[1] = (unsigned)rb[0];                      \
                fw[2] = (unsigned)ra[1]; fw[3] = (unsigned)rb[1];                      \
                pa[kvb * 2 + hh] = __builtin_bit_cast(u16x8, fw);                      \
            }                                                                          \
        }                                                                              \
        _Pragma("unroll")                                                              \
        for (int jk = 0; jk < 4; jk++) {                                               \
            lacc = mfma32(pa[jk], onesf, lacc);                                        \
            oacc[0] = mfma32(pa[jk], vf[0][jk], oacc[0]);                              \
            oacc[1] = mfma32(pa[jk], vf[1][jk], oacc[1]);                              \
        }                                                                              \
    }

#define STEP(SC, SN, cur)                                                       \
    {                                                                           \
        WAIT_VM(4);          /* drains own t-V and (t+1)-K; (t+1)-V in flight */\
        BARRIER;             /* partner's too */                                \
        READ_KF(cur ^ 1);                                                       \
        READ_VF(cur);                                                           \
        WAIT_LGKM0;                                                             \
        BARRIER;             /* pair done reading buf cur before overwrite */   \
        STAGE(cur);                                                             \
        QKNEXT(SN);                                                             \
        PACK_PV(SC);                                                            \
    }

    u16x8 kf[2][4], vf[2][4];
    f32x16 sA[2], sB[2];

    // ---- prologue: stage tiles 0,1 (8 loads each); sA = QK(0) ----
    STAGE(0);
    STAGE(1);
    WAIT_VM(12);         // own tile-0 K loads (oldest 4 of 16) landed
    BARRIER;             // partner's tile-0 K landed
    READ_KF(0);
    WAIT_LGKM0;
    QKNEXT(sA);

    // ---- main loop: 16 tiles ----
    for (int t = 0; t < 14; t += 2) {
        STEP(sA, sB, 0);   // consume even tile t
        STEP(sB, sA, 1);   // consume odd tile t+1
    }
    {   // t = 14: no stage
        WAIT_VM(4);
        BARRIER;
        READ_KF(1);
        READ_VF(0);
        WAIT_LGKM0;
        QKNEXT(sB);
        PACK_PV(sA);
    }
    {   // t = 15: PV only
        WAIT_VM(0);
        BARRIER;
        READ_VF(1);
        WAIT_LGKM0;
        PACK_PV(sB);
    }
#undef STAGE
#undef READ_KF
#undef READ_VF
#undef QKNEXT
#undef PACK_PV
#undef STEP

    // ---- combine epilogue (barrier BEFORE reusing staging LDS — R10 lesson) ----
    __syncthreads();
    float* Ox = (float*)&LDSB[0][0][0];   // [qh][32 crow][65 padded]
    float* lX = Ox + 2 * 32 * 65;         // [qh][32 crow]

    if (kvh == 1) {
#pragma unroll
        for (int reg = 0; reg < 16; reg++) {
            const int crow = (reg & 3) + 8 * (reg >> 2) + 4 * hi;
            Ox[qh * 2080 + crow * 65 + qL]      = oacc[0][reg];
            Ox[qh * 2080 + crow * 65 + 32 + qL] = oacc[1][reg];
            lX[qh * 32 + crow] = lacc[reg];
        }
    }
    __syncthreads();
    if (kvh == 0) {
#pragma unroll
        for (int reg = 0; reg < 16; reg++) {
            const int crow = (reg & 3) + 8 * (reg >> 2) + 4 * hi;
            const int row_c = qt * 64 + qh * 32 + crow;
            if (row_c < count) {
                float lt = lacc[reg] + lX[qh * 32 + crow];
                float linv = 1.0f / lt;
                float o0 = oacc[0][reg] + Ox[qh * 2080 + crow * 65 + qL];
                float o1 = oacc[1][reg] + Ox[qh * 2080 + crow * 65 + 32 + qL];
                const int orig = idxm[b * 2048 + row_c];
                long row = (long)b * Nseq + orig;       // scatter to ORIGINAL row
                res[row * 512 + h * 64 + qL]      = f2bf(o0 * linv);
                res[row * 512 + h * 64 + 32 + qL] = f2bf(o1 * linv);
            }
        }
    }
}

extern "C" void kernel_launch(void* const* d_in, const int* in_sizes, int n_in,
                              void* d_out, int out_size, void* d_ws, size_t ws_size,
                              hipStream_t stream) {
    const float* x   = (const float*)d_in[0];
    const int* mask  = (const int*)d_in[1];
    const float* Wq  = (const float*)d_in[2];
    const float* Wkv = (const float*)d_in[3];
    const float* Wo  = (const float*)d_in[4];
    float* out = (float*)d_out;

    const int D = 512;
    const long T = 8192;
    const float QSCALE = 0.125f * 1.4426950408889634f;  // d^-0.5 * log2(e)

    unsigned short* ws    = (unsigned short*)d_ws;
    unsigned short* xb    = ws;                          // T*512
    unsigned short* WqkvT = xb    + T * D;               // 1536*512
    unsigned short* WoT   = WqkvT + 1536L * 512;         // 512*512
    unsigned short* qkb   = WoT   + 512L * 512;          // T*1024
    unsigned short* vTb   = qkb   + T * 1024;            // 512*T
    unsigned short* resb  = vTb   + 512L * T;            // T*512 (original row positions)
    int* idxb = (int*)(resb + T * 512);                  // 4*2048 ints
    int* cntb = idxb + 4 * 2048;                         // 4 ints

    // merged: x->bf16 (4096 blocks) | weight transposes (384) | mask scan (4)
    preamble<<<4484, 256, 0, stream>>>(x, xb, Wq, Wkv, Wo, WqkvT, WoT, QSCALE,
                                       mask, idxb, cntb);

    // fused: qk (row-major) + vT (transposed write) = x @ [Wq*a|Wk|Wv]
    gemm_qkv<<<dim3(12, 64), 256, 0, stream>>>(xb, WqkvT, qkb, vTb);

    // attention (R17 structure): compacted q, paired-wave KVBLK=64, scatter to orig rows
    attn_kernel<<<1024, 256, 0, stream>>>(qkb, vTb, resb, idxb, cntb);

    // out = mask ? res @ Wo : 0   (128x64 tiles, 512 blocks = 2/CU)
    gemm_out<<<dim3(8, 64), 256, 0, stream>>>(resb, WoT, out, mask);
}